// Round 3
// baseline (5565.848 us; speedup 1.0000x reference)
//
#include <hip/hip_runtime.h>
#include <hip/hip_cooperative_groups.h>
#include <stdint.h>
#include <math.h>

namespace cg = cooperative_groups;

// ---------------- problem constants ----------------
#define P_     4
#define L_     32
#define H_     1024
#define NE_    132          // (L_+1)*P_ embedding vectors
#define G4_    4096         // 4*H
#define TEMP_  5.0f
#define TANHC_ 2.5f
#define TINY_  1.1754943508222875e-38f   // jnp.finfo(f32).tiny

#define PRNG_PARTITIONABLE 1

#define NBLK 128            // cooperative grid: 128 blocks x 512 thr (8 waves)
#define NTHR 512

// ---------------- device helpers ----------------
__device__ __forceinline__ float wave_reduce_sum(float v) {
  for (int off = 32; off; off >>= 1) v += __shfl_xor(v, off);
  return v;
}

__device__ __forceinline__ float sigmoidf_(float x) {
  return 0.5f + 0.5f * tanhf(0.5f * x);   // XLA logistic-via-tanh
}

// Threefry-2x32, 20 rounds
__device__ __forceinline__ void tf2x32(uint32_t k0, uint32_t k1,
                                       uint32_t& x0, uint32_t& x1) {
  uint32_t ks2 = k0 ^ k1 ^ 0x1BD11BDAu;
  x0 += k0; x1 += k1;
#define RR(r) { x0 += x1; x1 = (x1 << r) | (x1 >> (32 - r)); x1 ^= x0; }
  RR(13) RR(15) RR(26) RR(6)
  x0 += k1;  x1 += ks2 + 1u;
  RR(17) RR(29) RR(16) RR(24)
  x0 += ks2; x1 += k0 + 2u;
  RR(13) RR(15) RR(26) RR(6)
  x0 += k0;  x1 += k1 + 3u;
  RR(17) RR(29) RR(16) RR(24)
  x0 += k1;  x1 += ks2 + 4u;
  RR(13) RR(15) RR(26) RR(6)
  x0 += ks2; x1 += k0 + 5u;
#undef RR
}

// dot of one 1024-wide weight row with a 1024 vector; same FP order as r2's k1
__device__ __forceinline__ void dot_row(const float* __restrict__ wrow,
                                        const float* __restrict__ hv,
                                        int lane, float* dst) {
  float acc = 0.f;
  for (int it = 0; it < 4; ++it) {
    float4 w4 = *(const float4*)(wrow + lane * 4 + it * 256);
    float4 h4 = *(const float4*)(hv   + lane * 4 + it * 256);
    acc += w4.x * h4.x + w4.y * h4.y + w4.z * h4.z + w4.w * h4.w;
  }
  acc = wave_reduce_sum(acc);
  if (lane == 0) *dst = acc;
}

// ---------------- k_pre: Xp[p][e] = W_ih[p] @ emb[e] + b_ih[p] + b_hh[p] ----
__global__ __launch_bounds__(256) void k_pre(const float* __restrict__ emb,
                                             const float* __restrict__ w_ih,
                                             const float* __restrict__ b_ih,
                                             const float* __restrict__ b_hh,
                                             float* __restrict__ Xp) {
  int blk  = blockIdx.x;
  int p    = blk >> 8;
  int rg   = blk & 255;
  int wave = threadIdx.x >> 6;
  int lane = threadIdx.x & 63;
  int r0   = rg * 16 + wave * 4;

  const float* wbase = w_ih + ((size_t)p * G4_ + r0) * H_;
  float4 Wr[4][4];
  for (int q = 0; q < 4; ++q)
    for (int it = 0; it < 4; ++it)
      Wr[q][it] = *(const float4*)(wbase + (size_t)q * H_ + lane * 4 + it * 256);
  float bias[4];
  for (int q = 0; q < 4; ++q)
    bias[q] = b_ih[p * G4_ + r0 + q] + b_hh[p * G4_ + r0 + q];

  for (int e = 0; e < NE_; ++e) {
    const float* ev = emb + (size_t)e * H_;
    float4 x[4];
    for (int it = 0; it < 4; ++it)
      x[it] = *(const float4*)(ev + lane * 4 + it * 256);
    for (int q = 0; q < 4; ++q) {
      float acc = 0.f;
      for (int it = 0; it < 4; ++it)
        acc += Wr[q][it].x * x[it].x + Wr[q][it].y * x[it].y
             + Wr[q][it].z * x[it].z + Wr[q][it].w * x[it].w;
      acc = wave_reduce_sum(acc);
      if (lane == 0)
        Xp[((size_t)p * NE_ + e) * G4_ + r0 + q] = acc + bias[q];
    }
  }
}

// ---------------- persistent cooperative kernel ----------------
struct KA {
  const float *Xp, *w_hh, *w_a1, *w_a2, *w_idx;
  const int* seed;
  float *h;        // [4][1024]  current hidden (global commit)
  float *cbuf;     // [2][4][1024] cell state, layer-parity ping-pong
  float *Gbuf;     // [2][4][4096] W_hh@h, layer-parity ping-pong
  float *anchors;  // [128][1024]
  float *anchor2;  // [1024]
  float *logits;   // [128]
  int   *idx_buf;  // sampled node index
  int   *done_ctr; // [128] per-step logits-done counters
  float *out;      // [258]
};

__global__ __launch_bounds__(NTHR) void k_main(KA a) {
  cg::grid_group grid = cg::this_grid();
  const int blk  = blockIdx.x;
  const int tid  = threadIdx.x;
  const int wave = tid >> 6;
  const int lane = tid & 63;
  __shared__ __align__(16) float hsh[H_];
  __shared__ int sh_e;

  // ---- warm-up: block 0 computes warm cells (h=c=0 -> gates = Xp row) ----
  if (blk == 0) {
    for (int u = tid; u < P_ * H_; u += NTHR) {
      int p = u >> 10, j = u & 1023;
      const float* g = a.Xp + ((size_t)p * NE_ + (p * 33 + 32)) * G4_;
      float c2 = sigmoidf_(g[j]) * tanhf(g[j + 2048]);
      float h2 = sigmoidf_(g[j + 3072]) * tanhf(c2);
      a.h[u] = h2; a.cbuf[u] = c2;           // cbuf parity 0
    }
    for (int u = tid; u < 128; u += NTHR) a.done_ctr[u] = 0;
  }
  grid.sync();

  // ---- full k1 for layer 0: G(parity0) all paths + warm anchors[0..3] ----
  {
    int gw = blk * 8 + wave;                 // 0..1023
    for (int u = gw; u < 20480; u += NBLK * 8) {
      if (u < 16384) {
        int p = u >> 12, r = u & 4095;
        dot_row(a.w_hh + ((size_t)p * G4_ + r) * H_, a.h + p * H_, lane,
                a.Gbuf + (size_t)p * G4_ + r);
      } else {
        int v = u - 16384, p = v >> 10, r = v & 1023;
        dot_row(a.w_a1 + ((size_t)p * H_ + r) * H_, a.h + p * H_, lane,
                a.anchors + (size_t)p * H_ + r);
      }
    }
  }
  grid.sync();

  float ent_acc = 0.f, lp_acc = 0.f;

  for (int s = 0; s < 128; ++s) {
    const int l = s >> 2, p = s & 3;
    const int gpar = l & 1;
    const int n = 4 * (l + 1);

    // ================= phase A =================
    if (blk < 64) {
      // cell finish (each block redundantly -> LDS) + anchor2 rows
      if (tid == 0) {
        int e;
        if (l == 0) e = p * 33 + 32;
        else {
          int idx = __hip_atomic_load(a.idx_buf, __ATOMIC_ACQUIRE,
                                      __HIP_MEMORY_SCOPE_AGENT);
          e = (idx & 3) * 33 + (idx >> 2);
        }
        sh_e = e;
      }
      __syncthreads();
      const float* xrow = a.Xp + ((size_t)p * NE_ + sh_e) * G4_;
      const float* Gp = a.Gbuf + (size_t)gpar * P_ * G4_ + (size_t)p * G4_;
      const float* cp = a.cbuf + gpar * P_ * H_ + p * H_;
      float*       cq = a.cbuf + (gpar ^ 1) * P_ * H_ + p * H_;
      for (int j = tid; j < H_; j += NTHR) {
        float gi = Gp[j]        + xrow[j];
        float gf = Gp[j + 1024] + xrow[j + 1024];
        float gg = Gp[j + 2048] + xrow[j + 2048];
        float go = Gp[j + 3072] + xrow[j + 3072];
        float c2 = sigmoidf_(gf) * cp[j] + sigmoidf_(gi) * tanhf(gg);
        float h2 = sigmoidf_(go) * tanhf(c2);
        hsh[j] = h2;
        if (blk == 0) { a.h[p * H_ + j] = h2; cq[j] = c2; }
      }
      __syncthreads();
      for (int rr = 0; rr < 2; ++rr) {
        int r = blk * 16 + wave * 2 + rr;    // covers [0,1024)
        dot_row(a.w_a2 + ((size_t)p * H_ + r) * H_, hsh, lane, a.anchor2 + r);
      }
    } else if (s >= 1 && s - 1 < 124) {
      // leftover next-layer matvec rows of job (s-1): rows [3584, 5120)
      int js = s - 1, jl = js >> 2, jp = js & 3;
      const float* hv = a.h + jp * H_;
      float* Gn = a.Gbuf + (size_t)((jl + 1) & 1) * P_ * G4_ + (size_t)jp * G4_;
      float* an = a.anchors + (size_t)(4 * (jl + 1) + jp) * H_;
      int aw = (blk - 64) * 8 + wave;        // 0..511
      for (int u = 3584 + aw; u < 5120; u += 512) {
        if (u < 4096)
          dot_row(a.w_hh + ((size_t)jp * G4_ + u) * H_, hv, lane, Gn + u);
        else {
          int r1 = u - 4096;
          dot_row(a.w_a1 + ((size_t)jp * H_ + r1) * H_, hv, lane, an + r1);
        }
      }
    }
    grid.sync();

    // ================= phase B =================
    if (blk < 16) {
      // distributed logits (one row per wave) + in-phase sampler on block 0
      int r = blk * 8 + wave;
      if (r < n) {
        const float* pq = a.anchors + (size_t)r * H_;
        const float* wi = a.w_idx + p * H_;
        float acc = 0.f;
        for (int it = 0; it < 4; ++it) {
          float4 a4 = *(const float4*)(pq + lane * 4 + it * 256);
          float4 b4 = *(const float4*)(a.anchor2 + lane * 4 + it * 256);
          float4 w4 = *(const float4*)(wi + lane * 4 + it * 256);
          acc += tanhf(a4.x + b4.x) * w4.x + tanhf(a4.y + b4.y) * w4.y
               + tanhf(a4.z + b4.z) * w4.z + tanhf(a4.w + b4.w) * w4.w;
        }
        acc = wave_reduce_sum(acc);
        if (lane == 0)
          __hip_atomic_store(a.logits + r, TANHC_ * tanhf(acc / TEMP_),
                             __ATOMIC_RELEASE, __HIP_MEMORY_SCOPE_AGENT);
      }
      __syncthreads();
      if (tid == 0) { __threadfence(); atomicAdd(a.done_ctr + s, 1); }

      if (blk == 0 && wave == 0) {
        if (lane == 0) {
          while (__hip_atomic_load(a.done_ctr + s, __ATOMIC_ACQUIRE,
                                   __HIP_MEMORY_SCOPE_AGENT) < 16) {}
        }
        // lanes reconverge; sample (bit-exact JAX threefry Gumbel-max)
        uint32_t seed = (uint32_t)(*a.seed);
        uint32_t sk0 = 0u, sk1 = (uint32_t)s;
        tf2x32(0u, seed, sk0, sk1);
        float sv[2], lg[2]; int ii[2];
        for (int k = 0; k < 2; ++k) {
          int i = lane + 64 * k; ii[k] = i;
          if (i < n) {
#if PRNG_PARTITIONABLE
            uint32_t b0 = 0u, b1 = (uint32_t)i;
            tf2x32(sk0, sk1, b0, b1);
            uint32_t bits = b0 ^ b1;
#else
            int half = n >> 1;
            uint32_t c0 = (uint32_t)(i < half ? i : i - half);
            uint32_t c1 = (uint32_t)(i < half ? i + half : i);
            uint32_t r0 = c0, r1 = c1;
            tf2x32(sk0, sk1, r0, r1);
            uint32_t bits = (i < half) ? r0 : r1;
#endif
            uint32_t fb = (bits >> 9) | 0x3F800000u;
            float u = __uint_as_float(fb) - 1.0f;
            u = fmaxf(TINY_, u * (1.0f - TINY_) + TINY_);
            float g = -logf(-logf(u));
            lg[k] = __hip_atomic_load(a.logits + i, __ATOMIC_ACQUIRE,
                                      __HIP_MEMORY_SCOPE_AGENT);
            sv[k] = g + lg[k];
          } else { sv[k] = -INFINITY; lg[k] = -INFINITY; }
        }
        float bv; int bi;
        if (sv[0] >= sv[1]) { bv = sv[0]; bi = ii[0]; }
        else                { bv = sv[1]; bi = ii[1]; }
        for (int off = 32; off; off >>= 1) {
          float ov = __shfl_xor(bv, off);
          int   oi = __shfl_xor(bi, off);
          if (ov > bv || (ov == bv && oi < bi)) { bv = ov; bi = oi; }
        }
        float m = fmaxf(lg[0], lg[1]);
        for (int off = 32; off; off >>= 1) m = fmaxf(m, __shfl_xor(m, off));
        float se = 0.f;
        for (int k = 0; k < 2; ++k) if (ii[k] < n) se += expf(lg[k] - m);
        se = wave_reduce_sum(se);
        float lse = logf(se);
        float ent = 0.f;
        for (int k = 0; k < 2; ++k) if (ii[k] < n) {
          float lpv = (lg[k] - m) - lse;
          ent -= expf(lpv) * lpv;
        }
        ent = wave_reduce_sum(ent);
        if (lane == 0) {
          float li = __hip_atomic_load(a.logits + bi, __ATOMIC_ACQUIRE,
                                       __HIP_MEMORY_SCOPE_AGENT);
          ent_acc += ent;
          lp_acc  += -((li - m) - lse);
          a.out[s]       = (float)(bi & 3);   // arch % P
          a.out[128 + s] = (float)(bi >> 2);  // arch // P
          __hip_atomic_store(a.idx_buf, bi, __ATOMIC_RELEASE,
                             __HIP_MEMORY_SCOPE_AGENT);
        }
      }
    } else if (s < 124) {
      // bulk of job s: G_next rows [0, 3584)
      const float* hv = a.h + p * H_;
      float* Gn = a.Gbuf + (size_t)(gpar ^ 1) * P_ * G4_ + (size_t)p * G4_;
      int bw = (blk - 16) * 8 + wave;        // 0..895
      for (int u = bw; u < 3584; u += 896)
        dot_row(a.w_hh + ((size_t)p * G4_ + u) * H_, hv, lane, Gn + u);
    }
    grid.sync();
  }

  if (blk == 0 && tid == 0) { a.out[256] = ent_acc; a.out[257] = lp_acc; }
}

// ---------------- host ----------------
extern "C" void kernel_launch(void* const* d_in, const int* in_sizes, int n_in,
                              void* d_out, int out_size, void* d_ws, size_t ws_size,
                              hipStream_t stream) {
  (void)in_sizes; (void)n_in; (void)out_size; (void)ws_size;
  const float* emb   = (const float*)d_in[0];
  const float* w_ih  = (const float*)d_in[1];
  const float* w_hh  = (const float*)d_in[2];
  const float* b_ih  = (const float*)d_in[3];
  const float* b_hh  = (const float*)d_in[4];
  const float* w_a1  = (const float*)d_in[5];
  const float* w_a2  = (const float*)d_in[6];
  const float* w_idx = (const float*)d_in[7];
  const int*   seed  = (const int*)d_in[8];
  float* out = (float*)d_out;

  float* ws = (float*)d_ws;
  size_t o = 0;
  float* Xp      = ws + o; o += (size_t)P_ * NE_ * G4_;  // 2,162,688
  float* Gbuf    = ws + o; o += (size_t)2 * P_ * G4_;    // 32,768
  float* h       = ws + o; o += (size_t)P_ * H_;         // 4,096
  float* cbuf    = ws + o; o += (size_t)2 * P_ * H_;     // 8,192
  float* anchors = ws + o; o += (size_t)128 * H_;        // 131,072
  float* anchor2 = ws + o; o += H_;
  float* logits  = ws + o; o += 128;
  int*   idx_buf  = (int*)(ws + o); o += 64;
  int*   done_ctr = (int*)(ws + o); o += 128;

  k_pre<<<1024, 256, 0, stream>>>(emb, w_ih, b_ih, b_hh, Xp);

  KA ka;
  ka.Xp = Xp; ka.w_hh = w_hh; ka.w_a1 = w_a1; ka.w_a2 = w_a2; ka.w_idx = w_idx;
  ka.seed = seed;
  ka.h = h; ka.cbuf = cbuf; ka.Gbuf = Gbuf; ka.anchors = anchors;
  ka.anchor2 = anchor2; ka.logits = logits;
  ka.idx_buf = idx_buf; ka.done_ctr = done_ctr; ka.out = out;

  void* kp[] = { (void*)&ka };
  hipLaunchCooperativeKernel((const void*)k_main, dim3(NBLK), dim3(NTHR),
                             kp, 0, stream);
}

// Round 4
// 2478.769 us; speedup vs baseline: 2.2454x; 2.2454x over previous
//
#include <hip/hip_runtime.h>
#include <stdint.h>
#include <math.h>

// ---------------- problem constants ----------------
#define P_     4
#define L_     32
#define H_     1024
#define NE_    132          // (L_+1)*P_ embedding vectors
#define G4_    4096         // 4*H
#define TEMP_  5.0f
#define TANHC_ 2.5f
#define TINY_  1.1754943508222875e-38f   // jnp.finfo(f32).tiny

#define PRNG_PARTITIONABLE 1

// grid roles: block 0 = master, 1..16 = slicer+logits, 17..255 = workers
#define NBLK   256
#define NTHR   1024
#define NSLC   16
#define WBASE  17
#define NGANG  8

// ---------------- atomic helpers (agent scope = IF-coherent, L2-bypass) ----
__device__ __forceinline__ float at_ldf(const float* p) {
  return __hip_atomic_load(p, __ATOMIC_RELAXED, __HIP_MEMORY_SCOPE_AGENT);
}
__device__ __forceinline__ void at_stf(float* p, float v) {
  __hip_atomic_store(p, v, __ATOMIC_RELAXED, __HIP_MEMORY_SCOPE_AGENT);
}
__device__ __forceinline__ int at_ldi(const int* p) {
  return __hip_atomic_load(p, __ATOMIC_RELAXED, __HIP_MEMORY_SCOPE_AGENT);
}
__device__ __forceinline__ void at_sti(int* p, int v) {
  __hip_atomic_store(p, v, __ATOMIC_RELAXED, __HIP_MEMORY_SCOPE_AGENT);
}
// order: my preceding vmem stores reach the coherence point before anything after
__device__ __forceinline__ void vmwait() {
  asm volatile("s_waitcnt vmcnt(0)" ::: "memory");
}

// ---------------- math helpers (verbatim from r2 passing kernel) ----------
__device__ __forceinline__ float wave_reduce_sum(float v) {
  for (int off = 32; off; off >>= 1) v += __shfl_xor(v, off);
  return v;
}

__device__ __forceinline__ float sigmoidf_(float x) {
  return 0.5f + 0.5f * tanhf(0.5f * x);   // XLA logistic-via-tanh
}

__device__ __forceinline__ void tf2x32(uint32_t k0, uint32_t k1,
                                       uint32_t& x0, uint32_t& x1) {
  uint32_t ks2 = k0 ^ k1 ^ 0x1BD11BDAu;
  x0 += k0; x1 += k1;
#define RR(r) { x0 += x1; x1 = (x1 << r) | (x1 >> (32 - r)); x1 ^= x0; }
  RR(13) RR(15) RR(26) RR(6)
  x0 += k1;  x1 += ks2 + 1u;
  RR(17) RR(29) RR(16) RR(24)
  x0 += ks2; x1 += k0 + 2u;
  RR(13) RR(15) RR(26) RR(6)
  x0 += k0;  x1 += k1 + 3u;
  RR(17) RR(29) RR(16) RR(24)
  x0 += k1;  x1 += ks2 + 4u;
  RR(13) RR(15) RR(26) RR(6)
  x0 += ks2; x1 += k0 + 5u;
#undef RR
}

// one 1024-row dot: same FP order as r2's dot (w global, hv LDS or global)
__device__ __forceinline__ float dot_core(const float* __restrict__ wrow,
                                          const float* hv, int lane) {
  float acc = 0.f;
  for (int it = 0; it < 4; ++it) {
    float4 w4 = *(const float4*)(wrow + lane * 4 + it * 256);
    float4 h4 = *(const float4*)(hv   + lane * 4 + it * 256);
    acc += w4.x * h4.x + w4.y * h4.y + w4.z * h4.z + w4.w * h4.w;
  }
  return wave_reduce_sum(acc);
}

// ---------------- k_pre: Xp[p][e] = W_ih[p]@emb[e] + b_ih[p] + b_hh[p] ----
__global__ __launch_bounds__(256) void k_pre(const float* __restrict__ emb,
                                             const float* __restrict__ w_ih,
                                             const float* __restrict__ b_ih,
                                             const float* __restrict__ b_hh,
                                             float* __restrict__ Xp,
                                             int* __restrict__ flags) {
  int blk  = blockIdx.x;
  if (blk == 0) {                       // zero all sync flags/counters
    for (int i = threadIdx.x; i < 640; i += 256) flags[i] = 0;
  }
  int p    = blk >> 8;
  int rg   = blk & 255;
  int wave = threadIdx.x >> 6;
  int lane = threadIdx.x & 63;
  int r0   = rg * 16 + wave * 4;

  const float* wbase = w_ih + ((size_t)p * G4_ + r0) * H_;
  float4 Wr[4][4];
  for (int q = 0; q < 4; ++q)
    for (int it = 0; it < 4; ++it)
      Wr[q][it] = *(const float4*)(wbase + (size_t)q * H_ + lane * 4 + it * 256);
  float bias[4];
  for (int q = 0; q < 4; ++q)
    bias[q] = b_ih[p * G4_ + r0 + q] + b_hh[p * G4_ + r0 + q];

  for (int e = 0; e < NE_; ++e) {
    const float* ev = emb + (size_t)e * H_;
    float4 x[4];
    for (int it = 0; it < 4; ++it)
      x[it] = *(const float4*)(ev + lane * 4 + it * 256);
    for (int q = 0; q < 4; ++q) {
      float acc = 0.f;
      for (int it = 0; it < 4; ++it)
        acc += Wr[q][it].x * x[it].x + Wr[q][it].y * x[it].y
             + Wr[q][it].z * x[it].z + Wr[q][it].w * x[it].w;
      acc = wave_reduce_sum(acc);
      if (lane == 0)
        Xp[((size_t)p * NE_ + e) * G4_ + r0 + q] = acc + bias[q];
    }
  }
}

// ---------------- persistent kernel ----------------
struct KA {
  const float *Xp, *w_hh, *w_a1, *w_a2, *w_idx;
  const int* seed;
  float *h;        // [4][1024]   h commits (atomic)
  float *Gbuf;     // [2][4][4096] W_hh@h, layer-parity ping-pong (atomic)
  float *anchors;  // [128][1024] write-once rows (atomic store, cached reads)
  float *a2;       // [1024]      per-step anchor2 (atomic)
  float *logits;   // [128]       per-step logits (atomic)
  int   *flags;    // hready[128] gdone[128] adone[128] a2cnt[128] lcnt[128]
  float *out;      // [258]
};

__global__ __launch_bounds__(NTHR, 4) void k_main(KA a) {
  const int blk  = blockIdx.x;
  const int tid  = threadIdx.x;
  const int wave = tid >> 6;
  const int lane = tid & 63;
  __shared__ __align__(16) float lds[4096];   // master: c-state; others: h'/a2
  __shared__ int sh_i;

  int* hready = a.flags;
  int* gdone  = a.flags + 128;
  int* adone  = a.flags + 256;
  int* a2cnt  = a.flags + 384;
  int* lcnt   = a.flags + 512;

  if (blk == 0) {
    // ====================== MASTER ======================
    if (tid == 0) sh_i = 0;
    // warm-up cells (h=c=0 -> gates = Xp warm row), commit h per path ASAP
    for (int p = 0; p < P_; ++p) {
      const float* g = a.Xp + ((size_t)p * NE_ + (p * 33 + 32)) * G4_;
      int j = tid;                       // NTHR == H_
      float c2 = sigmoidf_(g[j]) * tanhf(g[j + 2048]);
      float h2 = sigmoidf_(g[j + 3072]) * tanhf(c2);
      lds[p * H_ + j] = c2;
      at_stf(a.h + p * H_ + j, h2);
      vmwait();
      __syncthreads();
      if (tid == 0) at_sti(hready + p, 1);
    }
    float ent_acc = 0.f, lp_acc = 0.f;
    for (int s = 0; s < 128; ++s) {
      const int l = s >> 2, p = s & 3, n = 4 * (l + 1);
      // wait for G job s (produced from h committed at step s-4 / warm)
      if (tid == 0) { while (at_ldi(gdone + s) < G4_) {} }
      __syncthreads();
      int idx = sh_i;
      int e = (l == 0) ? (p * 33 + 32) : ((idx & 3) * 33 + (idx >> 2));
      const float* xrow = a.Xp + ((size_t)p * NE_ + e) * G4_;
      const float* Gp = a.Gbuf + (size_t)(l & 1) * P_ * G4_ + (size_t)p * G4_;
      int j = tid;
      float gi = at_ldf(Gp + j)        + xrow[j];
      float gf = at_ldf(Gp + j + 1024) + xrow[j + 1024];
      float gg = at_ldf(Gp + j + 2048) + xrow[j + 2048];
      float go = at_ldf(Gp + j + 3072) + xrow[j + 3072];
      float c2 = sigmoidf_(gf) * lds[p * H_ + j] + sigmoidf_(gi) * tanhf(gg);
      float h2 = sigmoidf_(go) * tanhf(c2);
      lds[p * H_ + j] = c2;
      at_stf(a.h + p * H_ + j, h2);
      vmwait();
      __syncthreads();
      if (tid == 0) at_sti(hready + 4 + s, 1);

      // ---- sample on wave 0 once all n logits are committed ----
      if (wave == 0) {
        if (lane == 0) { while (at_ldi(lcnt + s) < n) {} }
        uint32_t seed = (uint32_t)(*a.seed);
        uint32_t sk0 = 0u, sk1 = (uint32_t)s;
        tf2x32(0u, seed, sk0, sk1);
        float sv[2], lg[2]; int ii[2];
        for (int k = 0; k < 2; ++k) {
          int i = lane + 64 * k; ii[k] = i;
          if (i < n) {
#if PRNG_PARTITIONABLE
            uint32_t b0 = 0u, b1 = (uint32_t)i;
            tf2x32(sk0, sk1, b0, b1);
            uint32_t bits = b0 ^ b1;
#else
            int half = n >> 1;
            uint32_t c0 = (uint32_t)(i < half ? i : i - half);
            uint32_t c1 = (uint32_t)(i < half ? i + half : i);
            uint32_t r0 = c0, r1 = c1;
            tf2x32(sk0, sk1, r0, r1);
            uint32_t bits = (i < half) ? r0 : r1;
#endif
            uint32_t fb = (bits >> 9) | 0x3F800000u;
            float u = __uint_as_float(fb) - 1.0f;
            u = fmaxf(TINY_, u * (1.0f - TINY_) + TINY_);
            float g = -logf(-logf(u));
            lg[k] = at_ldf(a.logits + i);
            sv[k] = g + lg[k];
          } else { sv[k] = -INFINITY; lg[k] = -INFINITY; }
        }
        float bv; int bi;
        if (sv[0] >= sv[1]) { bv = sv[0]; bi = ii[0]; }
        else                { bv = sv[1]; bi = ii[1]; }
        for (int off = 32; off; off >>= 1) {
          float ov = __shfl_xor(bv, off);
          int   oi = __shfl_xor(bi, off);
          if (ov > bv || (ov == bv && oi < bi)) { bv = ov; bi = oi; }
        }
        float m = fmaxf(lg[0], lg[1]);
        for (int off = 32; off; off >>= 1) m = fmaxf(m, __shfl_xor(m, off));
        float se = 0.f;
        for (int k = 0; k < 2; ++k) if (ii[k] < n) se += expf(lg[k] - m);
        se = wave_reduce_sum(se);
        float lse = logf(se);
        float ent = 0.f;
        for (int k = 0; k < 2; ++k) if (ii[k] < n) {
          float lpv = (lg[k] - m) - lse;
          ent -= expf(lpv) * lpv;
        }
        ent = wave_reduce_sum(ent);
        if (lane == 0) {
          float li = at_ldf(a.logits + bi);
          ent_acc += ent;
          lp_acc  += -((li - m) - lse);
          a.out[s]       = (float)(bi & 3);   // arch % P
          a.out[128 + s] = (float)(bi >> 2);  // arch // P
          sh_i = bi;
        }
      }
      __syncthreads();   // sh_i visible to all threads for next step's gather
    }
    if (tid == 0) { a.out[256] = ent_acc; a.out[257] = lp_acc; }

  } else if (blk <= NSLC) {
    // ====================== SLICER + LOGITS ======================
    const int sb = blk - 1;              // 0..15
    for (int s = 0; s < 128; ++s) {
      const int l = s >> 2, p = s & 3, n = 4 * (l + 1);
      if (tid == 0) { while (at_ldi(hready + 4 + s) == 0) {} }
      __syncthreads();
      lds[tid] = at_ldf(a.h + p * H_ + tid);   // h' -> LDS
      __syncthreads();
      // anchor2 slice: 64 rows/block, 4 per wave
      for (int q = 0; q < 4; ++q) {
        int r = sb * 64 + wave * 4 + q;
        float v = dot_core(a.w_a2 + ((size_t)p * H_ + r) * H_, lds, lane);
        if (lane == 0) at_stf(a.a2 + r, v);
      }
      vmwait();
      __syncthreads();
      if (tid == 0) {
        atomicAdd(a2cnt + s, 1);
        int base = s - p;                // newest 4 anchors jobs gate logits
        for (int k = 0; k < 4; ++k)
          while (at_ldi(adone + base + k) < H_) {}
        while (at_ldi(a2cnt + s) < NSLC) {}
      }
      __syncthreads();
      lds[tid] = at_ldf(a.a2 + tid);     // full anchor2 -> LDS (h' dead)
      __syncthreads();
      // logits rows: 8 per block on waves 0..7 (exact r2 k4 math)
      int r2 = sb * 8 + wave;
      if (wave < 8 && r2 < n) {
        const float* pq = a.anchors + (size_t)r2 * H_;   // write-once, cached
        const float* wi = a.w_idx + p * H_;
        float acc = 0.f;
        for (int it = 0; it < 4; ++it) {
          float4 a4 = *(const float4*)(pq + lane * 4 + it * 256);
          float4 b4 = *(const float4*)(&lds[lane * 4 + it * 256]);
          float4 w4 = *(const float4*)(wi + lane * 4 + it * 256);
          acc += tanhf(a4.x + b4.x) * w4.x + tanhf(a4.y + b4.y) * w4.y
               + tanhf(a4.z + b4.z) * w4.z + tanhf(a4.w + b4.w) * w4.w;
        }
        acc = wave_reduce_sum(acc);
        if (lane == 0) at_stf(a.logits + r2, TANHC_ * tanhf(acc / TEMP_));
      }
      vmwait();
      __syncthreads();
      if (tid == 0) {
        int nb = n - sb * 8;
        nb = nb < 0 ? 0 : (nb > 8 ? 8 : nb);
        if (nb > 0) atomicAdd(lcnt + s, nb);
      }
    }

  } else {
    // ====================== WORKERS ======================
    // job ev (0..127): from h-event ev; computes anchors row ev (w_attn1)
    // and G block for layer ev>>2 path ev&3 (w_hh). gang = ev & 7.
    const int w    = blk - WBASE;        // 0..238
    const int gang = w & 7, wi = w >> 3;
    const int gs   = (gang < 7) ? 30 : 29;
    for (int ev = gang; ev < 128; ev += NGANG) {
      const int jp = ev & 3, lj = ev >> 2;
      if (tid == 0) {
        while (at_ldi(hready + ev) == 0) __builtin_amdgcn_s_sleep(1);
      }
      __syncthreads();
      lds[tid] = at_ldf(a.h + jp * H_ + tid);   // h -> LDS
      __syncthreads();
      // anchors dots first (1-step deadline)
      int aLo = wi * H_ / gs, aHi = (wi + 1) * H_ / gs;
      const float* wa = a.w_a1 + (size_t)jp * H_ * H_;
      float* adst = a.anchors + (size_t)ev * H_;
      for (int d = aLo + wave; d < aHi; d += 16) {
        float v = dot_core(wa + (size_t)d * H_, lds, lane);
        if (lane == 0) at_stf(adst + d, v);
      }
      vmwait();
      __syncthreads();
      if (tid == 0) atomicAdd(adone + ev, aHi - aLo);
      // G dots (4-step deadline)
      int gLo = wi * G4_ / gs, gHi = (wi + 1) * G4_ / gs;
      const float* wg = a.w_hh + (size_t)jp * G4_ * H_;
      float* gdst = a.Gbuf + (size_t)(lj & 1) * P_ * G4_ + (size_t)jp * G4_;
      for (int d = gLo + wave; d < gHi; d += 16) {
        float v = dot_core(wg + (size_t)d * H_, lds, lane);
        if (lane == 0) at_stf(gdst + d, v);
      }
      vmwait();
      __syncthreads();
      if (tid == 0) atomicAdd(gdone + ev, gHi - gLo);
    }
  }
}

// ---------------- host ----------------
extern "C" void kernel_launch(void* const* d_in, const int* in_sizes, int n_in,
                              void* d_out, int out_size, void* d_ws, size_t ws_size,
                              hipStream_t stream) {
  (void)in_sizes; (void)n_in; (void)out_size; (void)ws_size;
  const float* emb   = (const float*)d_in[0];
  const float* w_ih  = (const float*)d_in[1];
  const float* w_hh  = (const float*)d_in[2];
  const float* b_ih  = (const float*)d_in[3];
  const float* b_hh  = (const float*)d_in[4];
  const float* w_a1  = (const float*)d_in[5];
  const float* w_a2  = (const float*)d_in[6];
  const float* w_idx = (const float*)d_in[7];
  const int*   seed  = (const int*)d_in[8];
  float* out = (float*)d_out;

  float* ws = (float*)d_ws;
  size_t o = 0;
  float* Xp      = ws + o; o += (size_t)P_ * NE_ * G4_;  // 2,162,688
  float* Gbuf    = ws + o; o += (size_t)2 * P_ * G4_;    // 32,768
  float* h       = ws + o; o += (size_t)P_ * H_;         // 4,096
  float* anchors = ws + o; o += (size_t)128 * H_;        // 131,072
  float* a2      = ws + o; o += H_;
  float* logits  = ws + o; o += 128;
  int*   flags   = (int*)(ws + o); o += 640;             // 5x128 ints

  k_pre<<<1024, 256, 0, stream>>>(emb, w_ih, b_ih, b_hh, Xp, flags);

  KA ka;
  ka.Xp = Xp; ka.w_hh = w_hh; ka.w_a1 = w_a1; ka.w_a2 = w_a2; ka.w_idx = w_idx;
  ka.seed = seed;
  ka.h = h; ka.Gbuf = Gbuf; ka.anchors = anchors; ka.a2 = a2;
  ka.logits = logits; ka.flags = flags; ka.out = out;

  void* kp[] = { (void*)&ka };
  hipLaunchCooperativeKernel((const void*)k_main, dim3(NBLK), dim3(NTHR),
                             kp, 0, stream);
}

// Round 5
// 1764.884 us; speedup vs baseline: 3.1537x; 1.4045x over previous
//
#include <hip/hip_runtime.h>
#include <stdint.h>
#include <math.h>

// ---------------- problem constants ----------------
#define P_     4
#define L_     32
#define H_     1024
#define NE_    132          // (L_+1)*P_ embedding vectors
#define G4_    4096         // 4*H
#define TEMP_  5.0f
#define TANHC_ 2.5f
#define TINY_  1.1754943508222875e-38f   // jnp.finfo(f32).tiny

#define PRNG_PARTITIONABLE 1

// grid roles: blk 0 = master; 1..64 = fused a2+logits; 65..255 = workers
#define NBLK   256
#define NTHR   512
#define NFUSE  64
#define WBASE  65

// ---------------- stamped-word + atomic helpers ----------------
__device__ __forceinline__ uint64_t pk(float v, uint32_t s) {
  union { float f; uint32_t u; } c; c.f = v;
  return ((uint64_t)s << 32) | c.u;
}
__device__ __forceinline__ float upk(uint64_t w) {
  union { uint32_t u; float f; } c; c.u = (uint32_t)w; return c.f;
}
__device__ __forceinline__ uint64_t ald64(const uint64_t* p) {
  return __hip_atomic_load(p, __ATOMIC_RELAXED, __HIP_MEMORY_SCOPE_AGENT);
}
__device__ __forceinline__ void ast64(uint64_t* p, uint64_t v) {
  __hip_atomic_store(p, v, __ATOMIC_RELAXED, __HIP_MEMORY_SCOPE_AGENT);
}
__device__ __forceinline__ void at_stf(float* p, float v) {
  __hip_atomic_store(p, v, __ATOMIC_RELAXED, __HIP_MEMORY_SCOPE_AGENT);
}
__device__ __forceinline__ int at_ldi(const int* p) {
  return __hip_atomic_load(p, __ATOMIC_RELAXED, __HIP_MEMORY_SCOPE_AGENT);
}
__device__ __forceinline__ void vmwait() {
  asm volatile("s_waitcnt vmcnt(0)" ::: "memory");
}

// ---------------- math helpers (verbatim FP order from r2/r4) -------------
__device__ __forceinline__ float wave_reduce_sum(float v) {
  for (int off = 32; off; off >>= 1) v += __shfl_xor(v, off);
  return v;
}
__device__ __forceinline__ float sigmoidf_(float x) {
  return 0.5f + 0.5f * tanhf(0.5f * x);   // XLA logistic-via-tanh
}
__device__ __forceinline__ void tf2x32(uint32_t k0, uint32_t k1,
                                       uint32_t& x0, uint32_t& x1) {
  uint32_t ks2 = k0 ^ k1 ^ 0x1BD11BDAu;
  x0 += k0; x1 += k1;
#define RR(r) { x0 += x1; x1 = (x1 << r) | (x1 >> (32 - r)); x1 ^= x0; }
  RR(13) RR(15) RR(26) RR(6)
  x0 += k1;  x1 += ks2 + 1u;
  RR(17) RR(29) RR(16) RR(24)
  x0 += ks2; x1 += k0 + 2u;
  RR(13) RR(15) RR(26) RR(6)
  x0 += k0;  x1 += k1 + 3u;
  RR(17) RR(29) RR(16) RR(24)
  x0 += k1;  x1 += ks2 + 4u;
  RR(13) RR(15) RR(26) RR(6)
  x0 += ks2; x1 += k0 + 5u;
#undef RR
}
__device__ __forceinline__ float dot_core(const float* __restrict__ wrow,
                                          const float* hv, int lane) {
  float acc = 0.f;
  for (int it = 0; it < 4; ++it) {
    float4 w4 = *(const float4*)(wrow + lane * 4 + it * 256);
    float4 h4 = *(const float4*)(hv   + lane * 4 + it * 256);
    acc += w4.x * h4.x + w4.y * h4.y + w4.z * h4.z + w4.w * h4.w;
  }
  return wave_reduce_sum(acc);
}

// ---------------- k_pre: Xp[p][e] = W_ih[p]@emb[e] + b_ih[p] + b_hh[p] ----
__global__ __launch_bounds__(256) void k_pre(const float* __restrict__ emb,
                                             const float* __restrict__ w_ih,
                                             const float* __restrict__ b_ih,
                                             const float* __restrict__ b_hh,
                                             float* __restrict__ Xp,
                                             int* __restrict__ adone) {
  int blk  = blockIdx.x;
  if (blk == 0 && threadIdx.x < 128) adone[threadIdx.x] = 0;
  int p    = blk >> 8;
  int rg   = blk & 255;
  int wave = threadIdx.x >> 6;
  int lane = threadIdx.x & 63;
  int r0   = rg * 16 + wave * 4;

  const float* wbase = w_ih + ((size_t)p * G4_ + r0) * H_;
  float4 Wr[4][4];
  for (int q = 0; q < 4; ++q)
    for (int it = 0; it < 4; ++it)
      Wr[q][it] = *(const float4*)(wbase + (size_t)q * H_ + lane * 4 + it * 256);
  float bias[4];
  for (int q = 0; q < 4; ++q)
    bias[q] = b_ih[p * G4_ + r0 + q] + b_hh[p * G4_ + r0 + q];

  for (int e = 0; e < NE_; ++e) {
    const float* ev = emb + (size_t)e * H_;
    float4 x[4];
    for (int it = 0; it < 4; ++it)
      x[it] = *(const float4*)(ev + lane * 4 + it * 256);
    for (int q = 0; q < 4; ++q) {
      float acc = 0.f;
      for (int it = 0; it < 4; ++it)
        acc += Wr[q][it].x * x[it].x + Wr[q][it].y * x[it].y
             + Wr[q][it].z * x[it].z + Wr[q][it].w * x[it].w;
      acc = wave_reduce_sum(acc);
      if (lane == 0)
        Xp[((size_t)p * NE_ + e) * G4_ + r0 + q] = acc + bias[q];
    }
  }
}

// ---------------- persistent kernel ----------------
struct KA {
  const float *Xp, *w_hh, *w_a1, *w_a2, *w_idx;
  const int* seed;
  uint64_t *hst;   // [4][1024] stamped h   (h-event ev -> slot ev&3, stamp ev+1)
  uint64_t *Gst;   // [4][4096] stamped W_hh@h (step s -> slot s&3, stamp s+1)
  float    *anc;   // [128][1024] anchors rows (plain values, agent stores)
  int      *adone; // [128] per-row completion counters (zeroed by k_pre)
  uint64_t *a2st;  // [1024] stamped anchor2 (stamp s+1)
  uint64_t *lst;   // [128]  stamped logits  (stamp s+1)
  float *out;      // [258]
};

__global__ __launch_bounds__(NTHR) void k_main(KA a) {
  const int blk  = blockIdx.x;
  const int tid  = threadIdx.x;
  const int wave = tid >> 6;
  const int lane = tid & 63;
  __shared__ __align__(16) float lds[4096];  // master: c[4][1024]; else h/a2
  __shared__ int sh_i;

  if (blk == 0) {
    // ====================== MASTER ======================
    // warm-up cells (h=c=0 -> gates = Xp warm row); stamp h-events 0..3
    for (int p = 0; p < P_; ++p) {
      const float* g = a.Xp + ((size_t)p * NE_ + (p * 33 + 32)) * G4_;
      for (int k = 0; k < 2; ++k) {
        int j = tid + k * 512;
        float c2 = sigmoidf_(g[j]) * tanhf(g[j + 2048]);
        float h2 = sigmoidf_(g[j + 3072]) * tanhf(c2);
        lds[p * H_ + j] = c2;
        ast64(a.hst + (size_t)p * H_ + j, pk(h2, p + 1));
      }
    }
    if (tid == 0) sh_i = 0;
    __syncthreads();

    float ent_acc = 0.f, lp_acc = 0.f;
    for (int s = 0; s < 128; ++s) {
      const int l = s >> 2, p = s & 3, n = 4 * (l + 1);
      const uint32_t st = (uint32_t)(s + 1);
      int idx = sh_i;
      int e = (l == 0) ? (p * 33 + 32) : ((idx & 3) * 33 + (idx >> 2));
      const float* xrow = a.Xp + ((size_t)p * NE_ + e) * G4_;
      const uint64_t* Gp = a.Gst + (size_t)p * G4_;

      // issue all 8 stamped G loads + 8 Xp loads, then verify stamps
      uint64_t wv[8]; float xv[8]; float cold[2];
      for (int k = 0; k < 2; ++k) {
        int j = tid + k * 512;
        for (int q = 0; q < 4; ++q) {
          wv[k * 4 + q] = ald64(Gp + j + q * 1024);
          xv[k * 4 + q] = xrow[j + q * 1024];
        }
        cold[k] = lds[p * H_ + j];
      }
      for (int k = 0; k < 2; ++k)
        for (int q = 0; q < 4; ++q) {
          int j = tid + k * 512;
          while ((uint32_t)(wv[k * 4 + q] >> 32) != st)
            wv[k * 4 + q] = ald64(Gp + j + q * 1024);
        }
      __syncthreads();          // all G reads complete before any h' store
      for (int k = 0; k < 2; ++k) {
        int j = tid + k * 512;
        float gi = upk(wv[k * 4 + 0]) + xv[k * 4 + 0];
        float gf = upk(wv[k * 4 + 1]) + xv[k * 4 + 1];
        float gg = upk(wv[k * 4 + 2]) + xv[k * 4 + 2];
        float go = upk(wv[k * 4 + 3]) + xv[k * 4 + 3];
        float c2 = sigmoidf_(gf) * cold[k] + sigmoidf_(gi) * tanhf(gg);
        float h2 = sigmoidf_(go) * tanhf(c2);
        lds[p * H_ + j] = c2;
        ast64(a.hst + (size_t)p * H_ + j, pk(h2, (uint32_t)(s + 5)));
      }

      if (wave == 0) {
        // ---- poll stamped logits, then bit-exact JAX Gumbel-max sample ----
        uint64_t lw[2]; int ii[2]; float lg[2], sv[2];
        for (int k = 0; k < 2; ++k) {
          int i = lane + 64 * k; ii[k] = i;
          if (i < n) lw[k] = ald64(a.lst + i);
        }
        for (int k = 0; k < 2; ++k)
          if (ii[k] < n)
            while ((uint32_t)(lw[k] >> 32) != st) lw[k] = ald64(a.lst + ii[k]);
        uint32_t seed = (uint32_t)(*a.seed);
        uint32_t sk0 = 0u, sk1 = (uint32_t)s;
        tf2x32(0u, seed, sk0, sk1);
        for (int k = 0; k < 2; ++k) {
          int i = ii[k];
          if (i < n) {
#if PRNG_PARTITIONABLE
            uint32_t b0 = 0u, b1 = (uint32_t)i;
            tf2x32(sk0, sk1, b0, b1);
            uint32_t bits = b0 ^ b1;
#else
            int half = n >> 1;
            uint32_t c0 = (uint32_t)(i < half ? i : i - half);
            uint32_t c1 = (uint32_t)(i < half ? i + half : i);
            uint32_t r0 = c0, r1 = c1;
            tf2x32(sk0, sk1, r0, r1);
            uint32_t bits = (i < half) ? r0 : r1;
#endif
            uint32_t fb = (bits >> 9) | 0x3F800000u;
            float u = __uint_as_float(fb) - 1.0f;
            u = fmaxf(TINY_, u * (1.0f - TINY_) + TINY_);
            float g = -logf(-logf(u));
            lg[k] = upk(lw[k]);
            sv[k] = g + lg[k];
          } else { sv[k] = -INFINITY; lg[k] = -INFINITY; }
        }
        float bv; int bi;
        if (sv[0] >= sv[1]) { bv = sv[0]; bi = ii[0]; }
        else                { bv = sv[1]; bi = ii[1]; }
        for (int off = 32; off; off >>= 1) {
          float ov = __shfl_xor(bv, off);
          int   oi = __shfl_xor(bi, off);
          if (ov > bv || (ov == bv && oi < bi)) { bv = ov; bi = oi; }
        }
        float m = fmaxf(lg[0], lg[1]);
        for (int off = 32; off; off >>= 1) m = fmaxf(m, __shfl_xor(m, off));
        float se = 0.f;
        for (int k = 0; k < 2; ++k) if (ii[k] < n) se += expf(lg[k] - m);
        se = wave_reduce_sum(se);
        float lse = logf(se);
        float ent = 0.f;
        for (int k = 0; k < 2; ++k) if (ii[k] < n) {
          float lpv = (lg[k] - m) - lse;
          ent -= expf(lpv) * lpv;
        }
        ent = wave_reduce_sum(ent);
        if (lane == 0) {
          float li = (bi == ii[0]) ? lg[0] : __shfl(lg[1], bi - 64);
          li = upk(ald64(a.lst + bi));   // exact logits[bi] (stamped, already s+1)
          ent_acc += ent;
          lp_acc  += -((li - m) - lse);
          a.out[s]       = (float)(bi & 3);   // arch % P
          a.out[128 + s] = (float)(bi >> 2);  // arch // P
          sh_i = bi;
        }
      }
      __syncthreads();   // sh_i visible for next step
    }
    if (tid == 0) { a.out[256] = ent_acc; a.out[257] = lp_acc; }

  } else if (blk <= NFUSE) {
    // ====================== FUSED a2 + logits ======================
    const int fb = blk - 1;              // 0..63; owns a2 rows [16fb,16fb+16)
    float4 areg[4]; bool haveA = false;  // reg-cached anchors row (waves 0/1)
    const int rl = 2 * fb + wave;        // logits row for waves 0,1
    for (int s = 0; s < 128; ++s) {
      const int p = s & 3, n = 4 * ((s >> 2) + 1);
      const uint32_t st = (uint32_t)(s + 1);
      const uint32_t hs = (uint32_t)(s + 5);
      __syncthreads();                   // protect lds reuse across steps
      {
        const uint64_t* hp = a.hst + (size_t)p * H_;
        uint64_t w0 = ald64(hp + tid), w1 = ald64(hp + tid + 512);
        while ((uint32_t)(w0 >> 32) != hs) w0 = ald64(hp + tid);
        while ((uint32_t)(w1 >> 32) != hs) w1 = ald64(hp + tid + 512);
        lds[tid] = upk(w0); lds[tid + 512] = upk(w1);
      }
      __syncthreads();
      // two anchor2 rows per wave (exact dot order)
      for (int q = 0; q < 2; ++q) {
        int r = fb * 16 + wave * 2 + q;
        float v = dot_core(a.w_a2 + ((size_t)p * H_ + r) * H_, lds, lane);
        if (lane == 0) ast64(a.a2st + r, pk(v, st));
      }
      bool active = (2 * fb) < n;        // block-uniform
      if (active) {
        // acquire this row's anchors into registers once (write-once data)
        if (wave < 2 && !haveA && rl < n) {
          while (at_ldi(a.adone + rl) < H_) __builtin_amdgcn_s_sleep(1);
          const float* ar = a.anc + (size_t)rl * H_;
          for (int it = 0; it < 4; ++it)
            areg[it] = *(const float4*)(ar + lane * 4 + it * 256);
          haveA = true;
        }
        // stage full stamped a2 into lds[1024..2048)
        {
          uint64_t w0 = ald64(a.a2st + tid), w1 = ald64(a.a2st + tid + 512);
          while ((uint32_t)(w0 >> 32) != st) w0 = ald64(a.a2st + tid);
          while ((uint32_t)(w1 >> 32) != st) w1 = ald64(a.a2st + tid + 512);
          lds[1024 + tid] = upk(w0); lds[1024 + tid + 512] = upk(w1);
        }
        __syncthreads();
        if (wave < 2 && rl < n) {        // exact r2 k4 math
          const float* wi = a.w_idx + p * H_;
          float acc = 0.f;
          for (int it = 0; it < 4; ++it) {
            float4 a4 = areg[it];
            float4 b4 = *(const float4*)(&lds[1024 + lane * 4 + it * 256]);
            float4 w4 = *(const float4*)(wi + lane * 4 + it * 256);
            acc += tanhf(a4.x + b4.x) * w4.x + tanhf(a4.y + b4.y) * w4.y
                 + tanhf(a4.z + b4.z) * w4.z + tanhf(a4.w + b4.w) * w4.w;
          }
          acc = wave_reduce_sum(acc);
          if (lane == 0) ast64(a.lst + rl, pk(TANHC_ * tanhf(acc / TEMP_), st));
        }
      }
    }

  } else {
    // ====================== WORKERS (path-stationary) ======================
    const int x  = blk - WBASE;          // 0..190
    const int p  = x & 3;
    const int w  = x >> 2;               // 0..47 (path<3) / 0..46 (path 3)
    const int nw = (p < 3) ? 48 : 47;
    const int aLo = w * H_  / nw, aHi = (w + 1) * H_  / nw;
    const int gLo = w * G4_ / nw, gHi = (w + 1) * G4_ / nw;
    const float* wa = a.w_a1 + (size_t)p * H_  * H_;
    const float* wg = a.w_hh + (size_t)p * G4_ * H_;
    for (int ev = p; ev < 128; ev += 4) {
      const uint32_t st = (uint32_t)(ev + 1);
      const uint64_t* hp = a.hst + (size_t)(ev & 3) * H_;
      __syncthreads();
      {
        uint64_t w0 = ald64(hp + tid), w1 = ald64(hp + tid + 512);
        while ((uint32_t)(w0 >> 32) != st) {
          __builtin_amdgcn_s_sleep(1); w0 = ald64(hp + tid);
        }
        while ((uint32_t)(w1 >> 32) != st) {
          __builtin_amdgcn_s_sleep(1); w1 = ald64(hp + tid + 512);
        }
        lds[tid] = upk(w0); lds[tid + 512] = upk(w1);
      }
      __syncthreads();
      // anchors elements first (1-step deadline): plain values + counter
      float* ad = a.anc + (size_t)ev * H_;
      for (int d = aLo + wave; d < aHi; d += 8) {
        float v = dot_core(wa + (size_t)d * H_, lds, lane);
        if (lane == 0) at_stf(ad + d, v);
      }
      vmwait();
      __syncthreads();
      if (tid == 0) atomicAdd(a.adone + ev, aHi - aLo);
      // G elements (4-step deadline): self-stamped
      uint64_t* gd = a.Gst + (size_t)(ev & 3) * G4_;
      for (int d = gLo + wave; d < gHi; d += 8) {
        float v = dot_core(wg + (size_t)d * H_, lds, lane);
        if (lane == 0) ast64(gd + d, pk(v, st));
      }
    }
  }
}

// ---------------- host ----------------
extern "C" void kernel_launch(void* const* d_in, const int* in_sizes, int n_in,
                              void* d_out, int out_size, void* d_ws, size_t ws_size,
                              hipStream_t stream) {
  (void)in_sizes; (void)n_in; (void)out_size; (void)ws_size;
  const float* emb   = (const float*)d_in[0];
  const float* w_ih  = (const float*)d_in[1];
  const float* w_hh  = (const float*)d_in[2];
  const float* b_ih  = (const float*)d_in[3];
  const float* b_hh  = (const float*)d_in[4];
  const float* w_a1  = (const float*)d_in[5];
  const float* w_a2  = (const float*)d_in[6];
  const float* w_idx = (const float*)d_in[7];
  const int*   seed  = (const int*)d_in[8];
  float* out = (float*)d_out;

  float* ws = (float*)d_ws;
  size_t o = 0;
  float*    Xp   = ws + o;              o += (size_t)P_ * NE_ * G4_; // 2,162,688
  uint64_t* hst  = (uint64_t*)(ws + o); o += 2 * 4 * H_;             // 8,192
  uint64_t* Gst  = (uint64_t*)(ws + o); o += 2 * 4 * G4_;            // 32,768
  float*    anc  = ws + o;              o += (size_t)128 * H_;       // 131,072
  uint64_t* a2st = (uint64_t*)(ws + o); o += 2 * H_;                 // 2,048
  uint64_t* lst  = (uint64_t*)(ws + o); o += 2 * 128;                // 256
  int*      adn  = (int*)(ws + o);      o += 128;

  k_pre<<<1024, 256, 0, stream>>>(emb, w_ih, b_ih, b_hh, Xp, adn);

  KA ka;
  ka.Xp = Xp; ka.w_hh = w_hh; ka.w_a1 = w_a1; ka.w_a2 = w_a2; ka.w_idx = w_idx;
  ka.seed = seed;
  ka.hst = hst; ka.Gst = Gst; ka.anc = anc; ka.adone = adn;
  ka.a2st = a2st; ka.lst = lst; ka.out = out;

  void* kp[] = { (void*)&ka };
  hipLaunchCooperativeKernel((const void*)k_main, dim3(NBLK), dim3(NTHR),
                             kp, 0, stream);
}